// Round 17
// baseline (767.717 us; speedup 1.0000x reference)
//
#include <hip/hip_runtime.h>

// HDVLUT R12: SINGLE fused tile kernel - sort, compute, write, all in LDS.
//
// R8-R11 (3-kernel counting-sort pipelines) all land 275-322us: floor =
// ~68us streaming + ~80-96us unsort random-gather leg (measured wall:
// ~175-240 Greq/s for ANY random gather, independent of footprint/MLP -
// R10 vs R11 proved occupancy/batching don't move it) + leg inefficiency.
// R12 removes ALL intermediate global traffic: per 64x128 tile, stage
// tile+halo u8 in LDS, counting-sort pixel indices by center value in LDS,
// then 32 groups x 8 values: stage 48KB LUT window (contiguous LUTG),
// process group's ~256 px (sh[l][j][n] gathers), write output DIRECTLY.
// One tile's scattered 8B out-stores share the block's XCD L2 -> lines
// complete before writeback (no R7 cross-XCD amplification).
// Traffic: img 35MB + LUTG 1.5MB x 1024 tiles (L2-resident) + out 134MB.
//
// LDS/block: stage 8580 + list 16384 + hist/starts/cur ~3KB + LUT 48KB
// = ~77KB -> 2 blocks/CU (gfx950 LDS = 160KB/CU; toolchain supports
// >64KB static per learn_hip 8-phase template's 128KB).
// ws: LUTG 1.5MB only. Fallback: R1 plain.
// R14/R15/R16 note: resubmits (GPU acquisition timeouts, no data).

typedef _Float16 h4 __attribute__((ext_vector_type(4)));
typedef float    f32x2 __attribute__((ext_vector_type(2)));

// LUTG[g][l][j][n]: g=value>>3 group, l=lut(0:H,1:V,2:D), j=value&7, n=nbr
__global__ __launch_bounds__(256) void p6_lutg(
    const float4* __restrict__ wh,
    const float4* __restrict__ wv,
    const float4* __restrict__ wd,
    h4* __restrict__ LUTG)
{
    int idx = blockIdx.x * 256 + threadIdx.x;   // 0 .. 196607
    int g = idx / 6144;
    int rem = idx - g * 6144;
    int l = rem >> 11;
    int rem2 = rem & 2047;
    int j = rem2 >> 8, n = rem2 & 255;
    const float4* src = (l == 0) ? wh : (l == 1) ? wv : wd;
    float4 f = src[((g * 8 + j) << 8) + n];
    h4 e;
    e[0] = (_Float16)f.x; e[1] = (_Float16)f.y;
    e[2] = (_Float16)f.z; e[3] = (_Float16)f.w;
    LUTG[idx] = e;
}

// One block = one 64x128 tile (8192 px). 256 threads.
__global__ __launch_bounds__(256) void p6_tile(
    const int* __restrict__ img,
    const h4* __restrict__ LUTG,
    float* __restrict__ out)
{
    __shared__ unsigned char stage[66 * 130];   // tile+halo values (u8)
    __shared__ unsigned short list[8192];       // px indices, value-sorted
    __shared__ unsigned hist[256], cur[256], starts[257];
    __shared__ h4 sh[6144];                     // 48KB: 8-value LUT window

    int t = threadIdx.x;
    int bid = blockIdx.x;
    int imgb = bid >> 5;
    int tile = bid & 31;
    int tileY = tile >> 2, tileX = tile & 3;    // 8 x 4 tiles
    int oy = tileY << 6, ox = tileX << 7;
    const int* I = img + ((size_t)imgb << 18);

    hist[t] = 0u;
    for (int l = t; l < 8580; l += 256) {
        int ly = l / 130, lx = l - ly * 130;
        int gy = oy + ly - 1; gy = (gy < 0) ? 0 : (gy > 511 ? 511 : gy);
        int gx = ox + lx - 1; gx = (gx < 0) ? 0 : (gx > 511 ? 511 : gx);
        stage[l] = (unsigned char)I[(gy << 9) + gx];
    }
    __syncthreads();

    // 256-bin histogram of center values
    for (int k = 0; k < 32; ++k) {
        int p = k * 256 + t;
        int ci = ((p >> 7) + 1) * 130 + (p & 127) + 1;
        atomicAdd(&hist[stage[ci]], 1u);
    }
    __syncthreads();

    // inclusive scan -> starts/cur
    cur[t] = hist[t];
    __syncthreads();
    for (int off = 1; off < 256; off <<= 1) {
        unsigned v = (t >= off) ? cur[t - off] : 0u;
        __syncthreads();
        cur[t] += v;
        __syncthreads();
    }
    starts[t] = cur[t] - hist[t];
    if (t == 255) starts[256] = cur[255];       // = 8192
    __syncthreads();
    cur[t] = starts[t];
    __syncthreads();

    // scatter pixel indices into value-sorted list
    for (int k = 0; k < 32; ++k) {
        int p = k * 256 + t;
        int ci = ((p >> 7) + 1) * 130 + (p & 127) + 1;
        unsigned v = stage[ci];
        unsigned slot = atomicAdd(&cur[v], 1u);
        list[slot] = (unsigned short)p;
    }
    __syncthreads();

    // 32 groups of 8 values
    for (int g = 0; g < 32; ++g) {
        #pragma unroll
        for (int i = 0; i < 24; ++i)
            sh[i * 256 + t] = LUTG[g * 6144 + i * 256 + t];
        __syncthreads();

        unsigned segs = starts[g * 8], sege = starts[g * 8 + 8];
        for (unsigned s = segs + t; s < sege; s += 256) {
            int p = list[s];
            int ly = p >> 7, lx = p & 127;
            int ci = (ly + 1) * 130 + lx + 1;
            unsigned a  = stage[ci];
            unsigned E  = stage[ci + 1],   W_ = stage[ci - 1];
            unsigned S  = stage[ci + 130], N_ = stage[ci - 130];
            unsigned SE = stage[ci + 131], SW = stage[ci + 129];
            unsigned NW = stage[ci - 131], NE = stage[ci - 129];
            int j = (int)(a & 7u) << 8;     // j*256
            h4 t4; float ax, ay, az, aw;
            t4 = sh[j + E];          ax  = (float)t4[0]; ay  = (float)t4[1]; az  = (float)t4[2]; aw  = (float)t4[3]; // E id
            t4 = sh[j + W_];         ax += (float)t4[3]; ay += (float)t4[2]; az += (float)t4[1]; aw += (float)t4[0]; // W rev
            t4 = sh[2048 + j + S];   ax += (float)t4[0]; ay += (float)t4[1]; az += (float)t4[2]; aw += (float)t4[3]; // S id
            t4 = sh[2048 + j + N_];  ax += (float)t4[3]; ay += (float)t4[2]; az += (float)t4[1]; aw += (float)t4[0]; // N rev
            t4 = sh[4096 + j + SE];  ax += (float)t4[0]; ay += (float)t4[1]; az += (float)t4[2]; aw += (float)t4[3]; // SE id
            t4 = sh[4096 + j + SW];  ax += (float)t4[2]; ay += (float)t4[0]; az += (float)t4[3]; aw += (float)t4[1]; // SW {2,0,3,1}
            t4 = sh[4096 + j + NW];  ax += (float)t4[3]; ay += (float)t4[2]; az += (float)t4[1]; aw += (float)t4[0]; // NW rev
            t4 = sh[4096 + j + NE];  ax += (float)t4[1]; ay += (float)t4[3]; az += (float)t4[0]; aw += (float)t4[2]; // NE {1,3,0,2}
            int x = ox + lx, y = oy + ly;
            size_t obase = ((((size_t)imgb << 10) + (size_t)(y << 1)) << 10) + (size_t)(x << 1);
            f32x2 lo; lo[0] = ax * 0.5f; lo[1] = ay * 0.5f;
            f32x2 hi; hi[0] = az * 0.5f; hi[1] = aw * 0.5f;
            __builtin_nontemporal_store(lo, (f32x2*)(out + obase));
            __builtin_nontemporal_store(hi, (f32x2*)(out + obase + 1024));
        }
        __syncthreads();
    }
}

// ---------------- R1 plain kernel (fallback) -------------------------------
__global__ __launch_bounds__(256) void hdvlut_plain(
    const int* __restrict__ img,
    const float4* __restrict__ wh,
    const float4* __restrict__ wd,
    const float4* __restrict__ wv,
    float* __restrict__ out)
{
    int idx = blockIdx.x * 256 + threadIdx.x;
    int x = idx & 511, y = (idx >> 9) & 511, b = idx >> 18;
    const int* I = img + ((size_t)b << 18);
    int row = y << 9;
    int xm = (x > 0) ? x - 1 : 0, xp = (x < 511) ? x + 1 : 511;
    int ym = (y > 0) ? y - 1 : 0, yp = (y < 511) ? y + 1 : 511;
    int rN = ym << 9, rS = yp << 9;
    int a = I[row|x], E = I[row|xp], W_ = I[row|xm], S = I[rS|x], N_ = I[rN|x];
    int SE = I[rS|xp], SW = I[rS|xm], NW = I[rN|xm], NE = I[rN|xp];
    int aL = a << 8;
    float4 t; float ax, ay, az, aw;
    t = wh[aL+E ]; ax  = t.x; ay  = t.y; az  = t.z; aw  = t.w;
    t = wh[aL+W_]; ax += t.w; ay += t.z; az += t.y; aw += t.x;
    t = wv[aL+S ]; ax += t.x; ay += t.y; az += t.z; aw += t.w;
    t = wv[aL+N_]; ax += t.w; ay += t.z; az += t.y; aw += t.x;
    t = wd[aL+SE]; ax += t.x; ay += t.y; az += t.z; aw += t.w;
    t = wd[aL+SW]; ax += t.z; ay += t.x; az += t.w; aw += t.y;
    t = wd[aL+NW]; ax += t.w; ay += t.z; az += t.y; aw += t.x;
    t = wd[aL+NE]; ax += t.y; ay += t.w; az += t.x; aw += t.z;
    size_t obase = ((((size_t)b << 10) + (y << 1)) << 10) + (x << 1);
    *(float2*)(out + obase)        = make_float2(ax*0.5f, ay*0.5f);
    *(float2*)(out + obase + 1024) = make_float2(az*0.5f, aw*0.5f);
}

extern "C" void kernel_launch(void* const* d_in, const int* in_sizes, int n_in,
                              void* d_out, int out_size, void* d_ws, size_t ws_size,
                              hipStream_t stream) {
    const int*    img = (const int*)d_in[0];
    const float4* wh  = (const float4*)d_in[1];
    const float4* wd  = (const float4*)d_in[2];
    const float4* wv  = (const float4*)d_in[3];
    float* out = (float*)d_out;

    int total = in_sizes[0];                      // B * 512 * 512
    size_t need = (size_t)196608 * 8;             // 1.5 MB LUTG

    if (ws_size >= need && (total & 262143) == 0) {
        h4* LUTG = (h4*)d_ws;
        hipLaunchKernelGGL(p6_lutg, dim3(768), dim3(256), 0, stream,
                           wh, wv, wd, LUTG);
        hipLaunchKernelGGL(p6_tile, dim3(total >> 13), dim3(256), 0, stream,
                           img, LUTG, out);
    } else {
        hipLaunchKernelGGL(hdvlut_plain, dim3(total / 256), dim3(256), 0, stream,
                           img, wh, wd, wv, out);
    }
}